// Round 3
// baseline (3302.702 us; speedup 1.0000x reference)
//
#include <hip/hip_runtime.h>

// ---------------- bf16 helpers ----------------

__device__ __forceinline__ unsigned short f2bf(float f) {
    unsigned u = __float_as_uint(f);
    unsigned r = (u + 0x7FFFu + ((u >> 16) & 1u)) >> 16;
    return (unsigned short)r;
}
__device__ __forceinline__ float bf2f(unsigned short u) {
    return __uint_as_float(((unsigned)u) << 16);
}

// ---------------- node GEMM + attention scores ----------------
// Hb[r][j] = bf16( sum_k X[r][k] * W[k][j] );  sc_s[r] = H[r].a_s;  sc_d[r] = H[r].a_d
// 8 rows per wave-iteration for ILP; W staged in LDS.
template<int K>
__global__ void gat_gemm_kernel(const float* __restrict__ X, const float* __restrict__ W,
                                const float* __restrict__ a_s, const float* __restrict__ a_d,
                                unsigned short* __restrict__ Hb, float* __restrict__ sc_s,
                                float* __restrict__ sc_d, int nrows) {
    __shared__ float Wl[K * 64];
    __shared__ float As[64];
    __shared__ float Ad[64];
    for (int i = threadIdx.x; i < K * 64; i += blockDim.x) Wl[i] = W[i];
    if (threadIdx.x < 64) {
        As[threadIdx.x] = a_s[threadIdx.x];
        Ad[threadIdx.x] = a_d[threadIdx.x];
    }
    __syncthreads();

    const int lane = threadIdx.x & 63;
    const int wave = threadIdx.x >> 6;
    const int wpb  = blockDim.x >> 6;
    const int gw   = blockIdx.x * wpb + wave;
    const int nw   = gridDim.x * wpb;
    const float asl = As[lane];
    const float adl = Ad[lane];

    const int ngroups = nrows >> 3;
    for (int g = gw; g < ngroups; g += nw) {
        const int r0 = g << 3;
        const float* xr = X + (size_t)r0 * K;
        float acc[8] = {0.f, 0.f, 0.f, 0.f, 0.f, 0.f, 0.f, 0.f};
#pragma unroll
        for (int k = 0; k < K; k += 4) {
            const float w0 = Wl[(k + 0) * 64 + lane];
            const float w1 = Wl[(k + 1) * 64 + lane];
            const float w2 = Wl[(k + 2) * 64 + lane];
            const float w3 = Wl[(k + 3) * 64 + lane];
#pragma unroll
            for (int r = 0; r < 8; r++) {
                float4 xv = *reinterpret_cast<const float4*>(xr + (size_t)r * K + k);
                acc[r] += xv.x * w0 + xv.y * w1 + xv.z * w2 + xv.w * w3;
            }
        }
#pragma unroll
        for (int r = 0; r < 8; r++) {
            Hb[(size_t)(r0 + r) * 64 + lane] = f2bf(acc[r]);
            float ps = acc[r] * asl;
            float pd = acc[r] * adl;
#pragma unroll
            for (int off = 32; off; off >>= 1) {
                ps += __shfl_down(ps, off);
                pd += __shfl_down(pd, off);
            }
            if (lane == 0) {
                sc_s[r0 + r] = ps;
                sc_d[r0 + r] = pd;
            }
        }
    }
    // tail rows (nrows % 8)
    for (int r = (ngroups << 3) + gw; r < nrows; r += nw) {
        const float* xr = X + (size_t)r * K;
        float acc = 0.f;
#pragma unroll
        for (int k = 0; k < K; k += 4) {
            float4 xv = *reinterpret_cast<const float4*>(xr + k);
            acc += xv.x * Wl[(k + 0) * 64 + lane] + xv.y * Wl[(k + 1) * 64 + lane]
                 + xv.z * Wl[(k + 2) * 64 + lane] + xv.w * Wl[(k + 3) * 64 + lane];
        }
        Hb[(size_t)r * 64 + lane] = f2bf(acc);
        float ps = acc * asl;
        float pd = acc * adl;
#pragma unroll
        for (int off = 32; off; off >>= 1) {
            ps += __shfl_down(ps, off);
            pd += __shfl_down(pd, off);
        }
        if (lane == 0) {
            sc_s[r] = ps;
            sc_d[r] = pd;
        }
    }
}

// ---------------- CSR build (once per launch; reused by both layers) ----------------

__global__ void hist_kernel(const int* __restrict__ dst, int* __restrict__ cnt, int E) {
    const int tid = blockIdx.x * blockDim.x + threadIdx.x;
    const int stride = gridDim.x * blockDim.x;
    const int E4 = E >> 2;
    for (int i = tid; i < E4; i += stride) {
        int4 d = reinterpret_cast<const int4*>(dst)[i];
        atomicAdd(&cnt[d.x], 1);
        atomicAdd(&cnt[d.y], 1);
        atomicAdd(&cnt[d.z], 1);
        atomicAdd(&cnt[d.w], 1);
    }
    for (int i = (E4 << 2) + tid; i < E; i += stride) atomicAdd(&cnt[dst[i]], 1);
}

// single-block exclusive scan of cnt[0..N-1] -> rowptr[0..N]
__global__ void scan_kernel(const int* __restrict__ cnt, int* __restrict__ rowptr, int N) {
    const int T = 1024;
    __shared__ int sums[T];
    const int t = threadIdx.x;
    const int chunk = (N + T - 1) / T;
    const int lo = t * chunk;
    const int hi = min(lo + chunk, N);
    int s = 0;
    for (int i = lo; i < hi; i++) s += cnt[i];
    sums[t] = s;
    __syncthreads();
    for (int off = 1; off < T; off <<= 1) {
        int u = (t >= off) ? sums[t - off] : 0;
        __syncthreads();
        sums[t] += u;
        __syncthreads();
    }
    int run = sums[t] - s;
    for (int i = lo; i < hi; i++) {
        rowptr[i] = run;
        run += cnt[i];
    }
    if (hi == N) rowptr[N] = run;
}

// dst-windowed scatter: pass p only places edges with dst in window p, so col[]
// writes land in a ~1.6MB cache-resident window (kills write-allocate blowup).
__global__ void scatter_kernel(const int* __restrict__ ei, const int* __restrict__ rowptr,
                               int* __restrict__ cursor, int* __restrict__ col,
                               int E, int N, int npass) {
    const int tid = blockIdx.x * blockDim.x + threadIdx.x;
    const int stride = gridDim.x * blockDim.x;
    const int win = (N + npass - 1) / npass;
    for (int p = 0; p < npass; p++) {
        const int lo = p * win;
        const int hi = min(lo + win, N);
        for (int e = tid; e < E; e += stride) {
            int d = ei[E + e];
            if (d >= lo && d < hi) {
                int pos = rowptr[d] + atomicAdd(&cursor[d], 1);
                col[pos] = ei[e];
            }
        }
    }
}

// ---------------- fused per-node online-softmax aggregation ----------------
template<bool RELU>
__global__ void gat_fused_agg(const int* __restrict__ rowptr, const int* __restrict__ col,
                              const float* __restrict__ sc_s, const float* __restrict__ sc_d,
                              const unsigned short* __restrict__ Hb, const float* __restrict__ bias,
                              float* __restrict__ Out, int N) {
    const int lane = threadIdx.x & 63;
    int gw = (blockIdx.x * blockDim.x + threadIdx.x) >> 6;
    const int nw = (gridDim.x * blockDim.x) >> 6;
    const float bl = bias[lane];
    for (int i = gw; i < N; i += nw) {
        const float scd = sc_d[i];
        float es = sc_s[i] + scd;
        es = es > 0.f ? es : 0.2f * es;   // self loop
        float m = es;
        float denom = 1.f;
        float acc = bf2f(Hb[(size_t)i * 64 + lane]);
        const int jb = rowptr[i], je = rowptr[i + 1];
        int j = jb;
        for (; j + 4 <= je; j += 4) {
            const int s0 = col[j], s1 = col[j + 1], s2 = col[j + 2], s3 = col[j + 3];
            float e0 = sc_s[s0] + scd;
            float e1 = sc_s[s1] + scd;
            float e2 = sc_s[s2] + scd;
            float e3 = sc_s[s3] + scd;
            e0 = e0 > 0.f ? e0 : 0.2f * e0;
            e1 = e1 > 0.f ? e1 : 0.2f * e1;
            e2 = e2 > 0.f ? e2 : 0.2f * e2;
            e3 = e3 > 0.f ? e3 : 0.2f * e3;
            const float h0 = bf2f(Hb[(size_t)s0 * 64 + lane]);
            const float h1 = bf2f(Hb[(size_t)s1 * 64 + lane]);
            const float h2 = bf2f(Hb[(size_t)s2 * 64 + lane]);
            const float h3 = bf2f(Hb[(size_t)s3 * 64 + lane]);
            const float mn = fmaxf(fmaxf(fmaxf(e0, e1), fmaxf(e2, e3)), m);
            const float scale = __expf(m - mn);
            const float w0 = __expf(e0 - mn);
            const float w1 = __expf(e1 - mn);
            const float w2 = __expf(e2 - mn);
            const float w3 = __expf(e3 - mn);
            denom = denom * scale + ((w0 + w1) + (w2 + w3));
            acc = acc * scale + w0 * h0 + w1 * h1 + w2 * h2 + w3 * h3;
            m = mn;
        }
        for (; j < je; j++) {
            const int s0 = col[j];
            float e0 = sc_s[s0] + scd;
            e0 = e0 > 0.f ? e0 : 0.2f * e0;
            const float h0 = bf2f(Hb[(size_t)s0 * 64 + lane]);
            const float mn = fmaxf(e0, m);
            const float scale = __expf(m - mn);
            const float w0 = __expf(e0 - mn);
            denom = denom * scale + w0;
            acc = acc * scale + w0 * h0;
            m = mn;
        }
        float o = acc / denom + bl;
        if (RELU) o = o > 0.f ? o : 0.f;
        Out[(size_t)i * 64 + lane] = o;
    }
}

// ---------------- pooling (batch is sorted: run-length accumulate) ----------------

__global__ void pool_kernel(const float* __restrict__ H, const int* __restrict__ batch,
                            float* __restrict__ sums, int* __restrict__ cnts, int N) {
    const int CHUNK = 256;
    const int lane = threadIdx.x & 63;
    int gw = (blockIdx.x * blockDim.x + threadIdx.x) >> 6;
    const int nw = (gridDim.x * blockDim.x) >> 6;
    const int nchunks = (N + CHUNK - 1) / CHUNK;
    for (int c = gw; c < nchunks; c += nw) {
        const int lo = c * CHUNK;
        const int hi = min(lo + CHUNK, N);
        int curb = batch[lo];
        float acc = 0.f;
        int cnt = 0;
        for (int n = lo; n < hi; n++) {
            int b = batch[n];
            if (b != curb) {
                unsafeAtomicAdd(&sums[(size_t)curb * 64 + lane], acc);
                if (lane == 0) atomicAdd(&cnts[curb], cnt);
                acc = 0.f; cnt = 0; curb = b;
            }
            acc += H[(size_t)n * 64 + lane];
            cnt++;
        }
        unsafeAtomicAdd(&sums[(size_t)curb * 64 + lane], acc);
        if (lane == 0) atomicAdd(&cnts[curb], cnt);
    }
}

// ---------------- final MLP + log_softmax ----------------
__global__ void mlp_kernel(const float* __restrict__ sums, const int* __restrict__ cnts,
                           const float* __restrict__ lw, const float* __restrict__ lb,
                           const float* __restrict__ cw, const float* __restrict__ cb,
                           float* __restrict__ out) {
    __shared__ float gv[64];
    __shared__ float z[32];
    __shared__ float logits[6];
    const int g = blockIdx.x;
    const int t = threadIdx.x;

    float cnt = (float)cnts[g];
    cnt = cnt > 1.f ? cnt : 1.f;
    gv[t] = sums[(size_t)g * 64 + t] / cnt;
    __syncthreads();

    if (t < 32) {
        float acc = lb[t];
#pragma unroll
        for (int k = 0; k < 64; k++) acc += gv[k] * lw[k * 32 + t];
        z[t] = acc > 0.f ? acc : 0.f;
    }
    __syncthreads();
    if (t < 6) {
        float acc = cb[t];
#pragma unroll
        for (int k = 0; k < 32; k++) acc += z[k] * cw[k * 6 + t];
        logits[t] = acc;
    }
    __syncthreads();
    if (t == 0) {
        float m = logits[0];
#pragma unroll
        for (int i = 1; i < 6; i++) m = fmaxf(m, logits[i]);
        float s = 0.f;
#pragma unroll
        for (int i = 0; i < 6; i++) s += expf(logits[i] - m);
        float lse = m + logf(s);
#pragma unroll
        for (int i = 0; i < 6; i++) out[(size_t)g * 6 + i] = logits[i] - lse;
    }
}

// ---------------- launch ----------------

extern "C" void kernel_launch(void* const* d_in, const int* in_sizes, int n_in,
                              void* d_out, int out_size, void* d_ws, size_t ws_size,
                              hipStream_t stream) {
    const float* x    = (const float*)d_in[0];
    const int*   ei   = (const int*)d_in[1];
    const int*   batch= (const int*)d_in[2];
    const float* W1   = (const float*)d_in[3];
    const float* as1  = (const float*)d_in[4];
    const float* ad1  = (const float*)d_in[5];
    const float* b1   = (const float*)d_in[6];
    const float* W2   = (const float*)d_in[7];
    const float* as2  = (const float*)d_in[8];
    const float* ad2  = (const float*)d_in[9];
    const float* b2   = (const float*)d_in[10];
    const float* lw   = (const float*)d_in[11];
    const float* lb   = (const float*)d_in[12];
    const float* cw   = (const float*)d_in[13];
    const float* cb   = (const float*)d_in[14];
    float* out = (float*)d_out;

    const int N  = in_sizes[0] / 128;
    const int E  = in_sizes[1] / 2;
    const int G  = out_size / 6;

    char* ws = (char*)d_ws;
    size_t off = 0;
    auto alloc = [&](size_t bytes) {
        void* p = ws + off;
        off += (bytes + 255) & ~size_t(255);
        return p;
    };
    float*          hB     = (float*)alloc((size_t)N * 64 * 4);
    unsigned short* Hb     = (unsigned short*)alloc((size_t)N * 64 * 2);
    float*          sc_s   = (float*)alloc((size_t)N * 4);
    float*          sc_d   = (float*)alloc((size_t)N * 4);
    int*            cnt    = (int*)alloc((size_t)N * 4);
    int*            cursor = (int*)alloc((size_t)N * 4);
    int*            rowptr = (int*)alloc((size_t)(N + 1) * 4);
    int*            colidx = (int*)alloc((size_t)E * 4);
    float*          psum   = (float*)alloc((size_t)G * 64 * 4);
    int*            pcnt   = (int*)alloc((size_t)G * 4);
    (void)ws_size;

    const int TB = 256;

    // ---- CSR build by dst ----
    hipMemsetAsync(cnt, 0, (size_t)N * 4, stream);
    hipMemsetAsync(cursor, 0, (size_t)N * 4, stream);
    hist_kernel<<<2048, TB, 0, stream>>>(ei + E, cnt, E);
    scan_kernel<<<1, 1024, 0, stream>>>(cnt, rowptr, N);
    scatter_kernel<<<2048, TB, 0, stream>>>(ei, rowptr, cursor, colidx, E, N, 8);

    // ---- layer 1 ----
    gat_gemm_kernel<128><<<1024, TB, 0, stream>>>(x, W1, as1, ad1, Hb, sc_s, sc_d, N);
    gat_fused_agg<true><<<2048, TB, 0, stream>>>(rowptr, colidx, sc_s, sc_d, Hb, b1, hB, N);

    // ---- layer 2 ----
    gat_gemm_kernel<64><<<1024, TB, 0, stream>>>(hB, W2, as2, ad2, Hb, sc_s, sc_d, N);
    gat_fused_agg<false><<<2048, TB, 0, stream>>>(rowptr, colidx, sc_s, sc_d, Hb, b2, hB, N);

    // ---- pooling + MLP head ----
    hipMemsetAsync(psum, 0, (size_t)G * 64 * 4, stream);
    hipMemsetAsync(pcnt, 0, (size_t)G * 4, stream);
    pool_kernel<<<128, TB, 0, stream>>>(hB, batch, psum, pcnt, N);
    mlp_kernel<<<G, 64, 0, stream>>>(psum, pcnt, lw, lb, cw, cb, out);
}

// Round 4
// 1753.360 us; speedup vs baseline: 1.8836x; 1.8836x over previous
//
#include <hip/hip_runtime.h>

// ---------------- bf16 helpers ----------------

__device__ __forceinline__ unsigned short f2bf(float f) {
    unsigned u = __float_as_uint(f);
    unsigned r = (u + 0x7FFFu + ((u >> 16) & 1u)) >> 16;
    return (unsigned short)r;
}
__device__ __forceinline__ float bf2f(unsigned short u) {
    return __uint_as_float(((unsigned)u) << 16);
}

// ---------------- node GEMM + attention scores ----------------
// 4 rows per wave-iteration: 4 independent FMA chains, ~40 VGPRs live.
// __launch_bounds__(256,2) -> VGPR cap 256, guaranteed no spill.
template<int K>
__global__ __launch_bounds__(256, 2)
void gat_gemm_kernel(const float* __restrict__ X, const float* __restrict__ W,
                     const float* __restrict__ a_s, const float* __restrict__ a_d,
                     unsigned short* __restrict__ Hb, float* __restrict__ sc_s,
                     float* __restrict__ sc_d, int nrows) {
    __shared__ float Wl[K * 64];
    for (int i = threadIdx.x; i < K * 64; i += blockDim.x) Wl[i] = W[i];
    __syncthreads();

    const int lane = threadIdx.x & 63;
    const float asl = a_s[lane];
    const float adl = a_d[lane];
    const int wave = threadIdx.x >> 6;
    const int wpb  = blockDim.x >> 6;
    const int gw   = blockIdx.x * wpb + wave;
    const int nw   = gridDim.x * wpb;

    const int ngroups = nrows >> 2;
    for (int g = gw; g < ngroups; g += nw) {
        const int r0 = g << 2;
        const float* x0 = X + (size_t)r0 * K;
        const float* x1 = x0 + K;
        const float* x2 = x1 + K;
        const float* x3 = x2 + K;
        float acc0 = 0.f, acc1 = 0.f, acc2 = 0.f, acc3 = 0.f;
#pragma unroll
        for (int k = 0; k < K; k += 4) {
            const float w0 = Wl[(k + 0) * 64 + lane];
            const float w1 = Wl[(k + 1) * 64 + lane];
            const float w2 = Wl[(k + 2) * 64 + lane];
            const float w3 = Wl[(k + 3) * 64 + lane];
            const float4 a = *reinterpret_cast<const float4*>(x0 + k);
            const float4 b = *reinterpret_cast<const float4*>(x1 + k);
            const float4 c = *reinterpret_cast<const float4*>(x2 + k);
            const float4 d = *reinterpret_cast<const float4*>(x3 + k);
            acc0 += a.x * w0 + a.y * w1 + a.z * w2 + a.w * w3;
            acc1 += b.x * w0 + b.y * w1 + b.z * w2 + b.w * w3;
            acc2 += c.x * w0 + c.y * w1 + c.z * w2 + c.w * w3;
            acc3 += d.x * w0 + d.y * w1 + d.z * w2 + d.w * w3;
        }
        float accs[4] = {acc0, acc1, acc2, acc3};
#pragma unroll
        for (int r = 0; r < 4; r++) {
            Hb[(size_t)(r0 + r) * 64 + lane] = f2bf(accs[r]);
            float ps = accs[r] * asl;
            float pd = accs[r] * adl;
#pragma unroll
            for (int off = 32; off; off >>= 1) {
                ps += __shfl_down(ps, off);
                pd += __shfl_down(pd, off);
            }
            if (lane == 0) {
                sc_s[r0 + r] = ps;
                sc_d[r0 + r] = pd;
            }
        }
    }
    // tail rows (nrows % 4)
    for (int r = (ngroups << 2) + gw; r < nrows; r += nw) {
        const float* xr = X + (size_t)r * K;
        float acc = 0.f;
#pragma unroll
        for (int k = 0; k < K; k += 4) {
            const float4 xv = *reinterpret_cast<const float4*>(xr + k);
            acc += xv.x * Wl[(k + 0) * 64 + lane] + xv.y * Wl[(k + 1) * 64 + lane]
                 + xv.z * Wl[(k + 2) * 64 + lane] + xv.w * Wl[(k + 3) * 64 + lane];
        }
        Hb[(size_t)r * 64 + lane] = f2bf(acc);
        float ps = acc * asl;
        float pd = acc * adl;
#pragma unroll
        for (int off = 32; off; off >>= 1) {
            ps += __shfl_down(ps, off);
            pd += __shfl_down(pd, off);
        }
        if (lane == 0) {
            sc_s[r] = ps;
            sc_d[r] = pd;
        }
    }
}

// ---------------- CSR build (once per launch; reused by both layers) ----------------

__global__ void hist_kernel(const int* __restrict__ dst, int* __restrict__ cnt, int E) {
    const int tid = blockIdx.x * blockDim.x + threadIdx.x;
    const int stride = gridDim.x * blockDim.x;
    const int E4 = E >> 2;
    for (int i = tid; i < E4; i += stride) {
        int4 d = reinterpret_cast<const int4*>(dst)[i];
        atomicAdd(&cnt[d.x], 1);
        atomicAdd(&cnt[d.y], 1);
        atomicAdd(&cnt[d.z], 1);
        atomicAdd(&cnt[d.w], 1);
    }
    for (int i = (E4 << 2) + tid; i < E; i += stride) atomicAdd(&cnt[dst[i]], 1);
}

// single-block exclusive scan of cnt[0..N-1] -> rowptr[0..N]
__global__ void scan_kernel(const int* __restrict__ cnt, int* __restrict__ rowptr, int N) {
    const int T = 1024;
    __shared__ int sums[T];
    const int t = threadIdx.x;
    const int chunk = (N + T - 1) / T;
    const int lo = t * chunk;
    const int hi = min(lo + chunk, N);
    int s = 0;
    for (int i = lo; i < hi; i++) s += cnt[i];
    sums[t] = s;
    __syncthreads();
    for (int off = 1; off < T; off <<= 1) {
        int u = (t >= off) ? sums[t - off] : 0;
        __syncthreads();
        sums[t] += u;
        __syncthreads();
    }
    int run = sums[t] - s;
    for (int i = lo; i < hi; i++) {
        rowptr[i] = run;
        run += cnt[i];
    }
    if (hi == N) rowptr[N] = run;
}

// dst-windowed scatter: pass p only places edges with dst in window p, so col[]
// writes land in a ~1.6MB cache-resident window (kills write-allocate blowup).
__global__ void scatter_kernel(const int* __restrict__ ei, const int* __restrict__ rowptr,
                               int* __restrict__ cursor, int* __restrict__ col,
                               int E, int N, int npass) {
    const int tid = blockIdx.x * blockDim.x + threadIdx.x;
    const int stride = gridDim.x * blockDim.x;
    const int win = (N + npass - 1) / npass;
    for (int p = 0; p < npass; p++) {
        const int lo = p * win;
        const int hi = min(lo + win, N);
        for (int e = tid; e < E; e += stride) {
            int d = ei[E + e];
            if (d >= lo && d < hi) {
                int pos = rowptr[d] + atomicAdd(&cursor[d], 1);
                col[pos] = ei[e];
            }
        }
    }
}

// ---------------- fused per-node online-softmax aggregation ----------------
template<bool RELU>
__global__ void gat_fused_agg(const int* __restrict__ rowptr, const int* __restrict__ col,
                              const float* __restrict__ sc_s, const float* __restrict__ sc_d,
                              const unsigned short* __restrict__ Hb, const float* __restrict__ bias,
                              float* __restrict__ Out, int N) {
    const int lane = threadIdx.x & 63;
    int gw = (blockIdx.x * blockDim.x + threadIdx.x) >> 6;
    const int nw = (gridDim.x * blockDim.x) >> 6;
    const float bl = bias[lane];
    for (int i = gw; i < N; i += nw) {
        const float scd = sc_d[i];
        float es = sc_s[i] + scd;
        es = es > 0.f ? es : 0.2f * es;   // self loop
        float m = es;
        float denom = 1.f;
        float acc = bf2f(Hb[(size_t)i * 64 + lane]);
        const int jb = rowptr[i], je = rowptr[i + 1];
        int j = jb;
        for (; j + 4 <= je; j += 4) {
            const int s0 = col[j], s1 = col[j + 1], s2 = col[j + 2], s3 = col[j + 3];
            float e0 = sc_s[s0] + scd;
            float e1 = sc_s[s1] + scd;
            float e2 = sc_s[s2] + scd;
            float e3 = sc_s[s3] + scd;
            e0 = e0 > 0.f ? e0 : 0.2f * e0;
            e1 = e1 > 0.f ? e1 : 0.2f * e1;
            e2 = e2 > 0.f ? e2 : 0.2f * e2;
            e3 = e3 > 0.f ? e3 : 0.2f * e3;
            const float h0 = bf2f(Hb[(size_t)s0 * 64 + lane]);
            const float h1 = bf2f(Hb[(size_t)s1 * 64 + lane]);
            const float h2 = bf2f(Hb[(size_t)s2 * 64 + lane]);
            const float h3 = bf2f(Hb[(size_t)s3 * 64 + lane]);
            const float mn = fmaxf(fmaxf(fmaxf(e0, e1), fmaxf(e2, e3)), m);
            const float scale = __expf(m - mn);
            const float w0 = __expf(e0 - mn);
            const float w1 = __expf(e1 - mn);
            const float w2 = __expf(e2 - mn);
            const float w3 = __expf(e3 - mn);
            denom = denom * scale + ((w0 + w1) + (w2 + w3));
            acc = acc * scale + w0 * h0 + w1 * h1 + w2 * h2 + w3 * h3;
            m = mn;
        }
        for (; j < je; j++) {
            const int s0 = col[j];
            float e0 = sc_s[s0] + scd;
            e0 = e0 > 0.f ? e0 : 0.2f * e0;
            const float h0 = bf2f(Hb[(size_t)s0 * 64 + lane]);
            const float mn = fmaxf(e0, m);
            const float scale = __expf(m - mn);
            const float w0 = __expf(e0 - mn);
            denom = denom * scale + w0;
            acc = acc * scale + w0 * h0;
            m = mn;
        }
        float o = acc / denom + bl;
        if (RELU) o = o > 0.f ? o : 0.f;
        Out[(size_t)i * 64 + lane] = o;
    }
}

// ---------------- pooling (batch is sorted: run-length accumulate) ----------------

__global__ void pool_kernel(const float* __restrict__ H, const int* __restrict__ batch,
                            float* __restrict__ sums, int* __restrict__ cnts, int N) {
    const int CHUNK = 256;
    const int lane = threadIdx.x & 63;
    int gw = (blockIdx.x * blockDim.x + threadIdx.x) >> 6;
    const int nw = (gridDim.x * blockDim.x) >> 6;
    const int nchunks = (N + CHUNK - 1) / CHUNK;
    for (int c = gw; c < nchunks; c += nw) {
        const int lo = c * CHUNK;
        const int hi = min(lo + CHUNK, N);
        int curb = batch[lo];
        float acc = 0.f;
        int cnt = 0;
        for (int n = lo; n < hi; n++) {
            int b = batch[n];
            if (b != curb) {
                unsafeAtomicAdd(&sums[(size_t)curb * 64 + lane], acc);
                if (lane == 0) atomicAdd(&cnts[curb], cnt);
                acc = 0.f; cnt = 0; curb = b;
            }
            acc += H[(size_t)n * 64 + lane];
            cnt++;
        }
        unsafeAtomicAdd(&sums[(size_t)curb * 64 + lane], acc);
        if (lane == 0) atomicAdd(&cnts[curb], cnt);
    }
}

// ---------------- final MLP + log_softmax ----------------
__global__ void mlp_kernel(const float* __restrict__ sums, const int* __restrict__ cnts,
                           const float* __restrict__ lw, const float* __restrict__ lb,
                           const float* __restrict__ cw, const float* __restrict__ cb,
                           float* __restrict__ out) {
    __shared__ float gv[64];
    __shared__ float z[32];
    __shared__ float logits[6];
    const int g = blockIdx.x;
    const int t = threadIdx.x;

    float cnt = (float)cnts[g];
    cnt = cnt > 1.f ? cnt : 1.f;
    gv[t] = sums[(size_t)g * 64 + t] / cnt;
    __syncthreads();

    if (t < 32) {
        float acc = lb[t];
#pragma unroll
        for (int k = 0; k < 64; k++) acc += gv[k] * lw[k * 32 + t];
        z[t] = acc > 0.f ? acc : 0.f;
    }
    __syncthreads();
    if (t < 6) {
        float acc = cb[t];
#pragma unroll
        for (int k = 0; k < 32; k++) acc += z[k] * cw[k * 6 + t];
        logits[t] = acc;
    }
    __syncthreads();
    if (t == 0) {
        float m = logits[0];
#pragma unroll
        for (int i = 1; i < 6; i++) m = fmaxf(m, logits[i]);
        float s = 0.f;
#pragma unroll
        for (int i = 0; i < 6; i++) s += expf(logits[i] - m);
        float lse = m + logf(s);
#pragma unroll
        for (int i = 0; i < 6; i++) out[(size_t)g * 6 + i] = logits[i] - lse;
    }
}

// ---------------- launch ----------------

extern "C" void kernel_launch(void* const* d_in, const int* in_sizes, int n_in,
                              void* d_out, int out_size, void* d_ws, size_t ws_size,
                              hipStream_t stream) {
    const float* x    = (const float*)d_in[0];
    const int*   ei   = (const int*)d_in[1];
    const int*   batch= (const int*)d_in[2];
    const float* W1   = (const float*)d_in[3];
    const float* as1  = (const float*)d_in[4];
    const float* ad1  = (const float*)d_in[5];
    const float* b1   = (const float*)d_in[6];
    const float* W2   = (const float*)d_in[7];
    const float* as2  = (const float*)d_in[8];
    const float* ad2  = (const float*)d_in[9];
    const float* b2   = (const float*)d_in[10];
    const float* lw   = (const float*)d_in[11];
    const float* lb   = (const float*)d_in[12];
    const float* cw   = (const float*)d_in[13];
    const float* cb   = (const float*)d_in[14];
    float* out = (float*)d_out;

    const int N  = in_sizes[0] / 128;
    const int E  = in_sizes[1] / 2;
    const int G  = out_size / 6;

    char* ws = (char*)d_ws;
    size_t off = 0;
    auto alloc = [&](size_t bytes) {
        void* p = ws + off;
        off += (bytes + 255) & ~size_t(255);
        return p;
    };
    float*          hB     = (float*)alloc((size_t)N * 64 * 4);
    unsigned short* Hb     = (unsigned short*)alloc((size_t)N * 64 * 2);
    float*          sc_s   = (float*)alloc((size_t)N * 4);
    float*          sc_d   = (float*)alloc((size_t)N * 4);
    int*            cnt    = (int*)alloc((size_t)N * 4);
    int*            cursor = (int*)alloc((size_t)N * 4);
    int*            rowptr = (int*)alloc((size_t)(N + 1) * 4);
    int*            colidx = (int*)alloc((size_t)E * 4);
    float*          psum   = (float*)alloc((size_t)G * 64 * 4);
    int*            pcnt   = (int*)alloc((size_t)G * 4);
    (void)ws_size;

    const int TB = 256;

    // ---- CSR build by dst ----
    hipMemsetAsync(cnt, 0, (size_t)N * 4, stream);
    hipMemsetAsync(cursor, 0, (size_t)N * 4, stream);
    hist_kernel<<<2048, TB, 0, stream>>>(ei + E, cnt, E);
    scan_kernel<<<1, 1024, 0, stream>>>(cnt, rowptr, N);
    scatter_kernel<<<2048, TB, 0, stream>>>(ei, rowptr, cursor, colidx, E, N, 8);

    // ---- layer 1 ----
    gat_gemm_kernel<128><<<1024, TB, 0, stream>>>(x, W1, as1, ad1, Hb, sc_s, sc_d, N);
    gat_fused_agg<true><<<2048, TB, 0, stream>>>(rowptr, colidx, sc_s, sc_d, Hb, b1, hB, N);

    // ---- layer 2 ----
    gat_gemm_kernel<64><<<1024, TB, 0, stream>>>(hB, W2, as2, ad2, Hb, sc_s, sc_d, N);
    gat_fused_agg<false><<<2048, TB, 0, stream>>>(rowptr, colidx, sc_s, sc_d, Hb, b2, hB, N);

    // ---- pooling + MLP head ----
    hipMemsetAsync(psum, 0, (size_t)G * 64 * 4, stream);
    hipMemsetAsync(pcnt, 0, (size_t)G * 4, stream);
    pool_kernel<<<128, TB, 0, stream>>>(hB, batch, psum, pcnt, N);
    mlp_kernel<<<G, 64, 0, stream>>>(psum, pcnt, lw, lb, cw, cb, out);
}

// Round 5
// 913.760 us; speedup vs baseline: 3.6144x; 1.9188x over previous
//
#include <hip/hip_runtime.h>

// ---------------- bf16 helpers ----------------

__device__ __forceinline__ unsigned short f2bf(float f) {
    unsigned u = __float_as_uint(f);
    unsigned r = (u + 0x7FFFu + ((u >> 16) & 1u)) >> 16;
    return (unsigned short)r;
}
__device__ __forceinline__ float bf2f(unsigned short u) {
    return __uint_as_float(((unsigned)u) << 16);
}

// ---------------- node GEMM + attention scores ----------------
// One 64-row tile per block. X tile staged in LDS via coalesced per-lane
// float4 loads (NO wave-uniform global loads -> no unroll-hoist spill).
// Each wave computes 16 rows as 4 groups of 4 independent FMA chains.
template<int K>
__global__ __launch_bounds__(256, 2)
void gat_gemm_kernel(const float* __restrict__ X, const float* __restrict__ W,
                     const float* __restrict__ a_s, const float* __restrict__ a_d,
                     unsigned short* __restrict__ Hb, float* __restrict__ sc_s,
                     float* __restrict__ sc_d, int nrows) {
    __shared__ float Wl[K * 64];
    __shared__ float Xl[64 * K];

    const int tid = threadIdx.x;
    const int tile0 = blockIdx.x * 64;

    // stage W
    for (int i = tid; i < K * 64 / 4; i += 256)
        reinterpret_cast<float4*>(Wl)[i] = reinterpret_cast<const float4*>(W)[i];
    // stage X tile (coalesced: consecutive threads -> consecutive float4)
    for (int i = tid; i < 64 * K / 4; i += 256) {
        const int row = i / (K / 4);
        const int gr = tile0 + row;
        float4 v = make_float4(0.f, 0.f, 0.f, 0.f);
        if (gr < nrows) v = reinterpret_cast<const float4*>(X)[(size_t)gr * (K / 4) + (i % (K / 4))];
        reinterpret_cast<float4*>(Xl)[i] = v;
    }
    __syncthreads();

    const int lane = tid & 63;
    const int wave = tid >> 6;
    const float asl = a_s[lane];
    const float adl = a_d[lane];

#pragma unroll
    for (int g = 0; g < 4; g++) {
        const int r0 = wave * 16 + g * 4;      // local row of group start
        if (tile0 + r0 >= nrows) break;
        float acc0 = 0.f, acc1 = 0.f, acc2 = 0.f, acc3 = 0.f;
        const float* xp0 = Xl + (size_t)(r0 + 0) * K;
        const float* xp1 = Xl + (size_t)(r0 + 1) * K;
        const float* xp2 = Xl + (size_t)(r0 + 2) * K;
        const float* xp3 = Xl + (size_t)(r0 + 3) * K;
#pragma unroll 2
        for (int k = 0; k < K; k += 4) {
            const float4 a = *reinterpret_cast<const float4*>(xp0 + k);
            const float4 b = *reinterpret_cast<const float4*>(xp1 + k);
            const float4 c = *reinterpret_cast<const float4*>(xp2 + k);
            const float4 d = *reinterpret_cast<const float4*>(xp3 + k);
            const float w0 = Wl[(k + 0) * 64 + lane];
            const float w1 = Wl[(k + 1) * 64 + lane];
            const float w2 = Wl[(k + 2) * 64 + lane];
            const float w3 = Wl[(k + 3) * 64 + lane];
            acc0 += a.x * w0 + a.y * w1 + a.z * w2 + a.w * w3;
            acc1 += b.x * w0 + b.y * w1 + b.z * w2 + b.w * w3;
            acc2 += c.x * w0 + c.y * w1 + c.z * w2 + c.w * w3;
            acc3 += d.x * w0 + d.y * w1 + d.z * w2 + d.w * w3;
        }
        const float accs[4] = {acc0, acc1, acc2, acc3};
#pragma unroll
        for (int r = 0; r < 4; r++) {
            const int gr = tile0 + r0 + r;
            if (gr >= nrows) break;
            Hb[(size_t)gr * 64 + lane] = f2bf(accs[r]);
            float ps = accs[r] * asl;
            float pd = accs[r] * adl;
#pragma unroll
            for (int off = 32; off; off >>= 1) {
                ps += __shfl_down(ps, off);
                pd += __shfl_down(pd, off);
            }
            if (lane == 0) {
                sc_s[gr] = ps;
                sc_d[gr] = pd;
            }
        }
    }
}

// ---------------- CSR build (once per launch; reused by both layers) ----------------

__global__ void hist_kernel(const int* __restrict__ dst, int* __restrict__ cnt, int E) {
    const int tid = blockIdx.x * blockDim.x + threadIdx.x;
    const int stride = gridDim.x * blockDim.x;
    const int E4 = E >> 2;
    for (int i = tid; i < E4; i += stride) {
        int4 d = reinterpret_cast<const int4*>(dst)[i];
        atomicAdd(&cnt[d.x], 1);
        atomicAdd(&cnt[d.y], 1);
        atomicAdd(&cnt[d.z], 1);
        atomicAdd(&cnt[d.w], 1);
    }
    for (int i = (E4 << 2) + tid; i < E; i += stride) atomicAdd(&cnt[dst[i]], 1);
}

// single-block exclusive scan of cnt[0..N-1] -> rowptr[0..N]
__global__ void scan_kernel(const int* __restrict__ cnt, int* __restrict__ rowptr, int N) {
    const int T = 1024;
    __shared__ int sums[T];
    const int t = threadIdx.x;
    const int chunk = (N + T - 1) / T;
    const int lo = t * chunk;
    const int hi = min(lo + chunk, N);
    int s = 0;
    for (int i = lo; i < hi; i++) s += cnt[i];
    sums[t] = s;
    __syncthreads();
    for (int off = 1; off < T; off <<= 1) {
        int u = (t >= off) ? sums[t - off] : 0;
        __syncthreads();
        sums[t] += u;
        __syncthreads();
    }
    int run = sums[t] - s;
    for (int i = lo; i < hi; i++) {
        rowptr[i] = run;
        run += cnt[i];
    }
    if (hi == N) rowptr[N] = run;
}

// dst-windowed scatter: pass p only places edges with dst in window p, so col[]
// writes land in a ~1.6MB cache-resident window (kills write-allocate blowup).
__global__ void scatter_kernel(const int* __restrict__ ei, const int* __restrict__ rowptr,
                               int* __restrict__ cursor, int* __restrict__ col,
                               int E, int N, int npass) {
    const int tid = blockIdx.x * blockDim.x + threadIdx.x;
    const int stride = gridDim.x * blockDim.x;
    const int win = (N + npass - 1) / npass;
    for (int p = 0; p < npass; p++) {
        const int lo = p * win;
        const int hi = min(lo + win, N);
        for (int e = tid; e < E; e += stride) {
            int d = ei[E + e];
            if (d >= lo && d < hi) {
                int pos = rowptr[d] + atomicAdd(&cursor[d], 1);
                col[pos] = ei[e];
            }
        }
    }
}

// ---------------- fused per-node online-softmax aggregation ----------------
template<bool RELU>
__global__ void gat_fused_agg(const int* __restrict__ rowptr, const int* __restrict__ col,
                              const float* __restrict__ sc_s, const float* __restrict__ sc_d,
                              const unsigned short* __restrict__ Hb, const float* __restrict__ bias,
                              float* __restrict__ Out, int N) {
    const int lane = threadIdx.x & 63;
    int gw = (blockIdx.x * blockDim.x + threadIdx.x) >> 6;
    const int nw = (gridDim.x * blockDim.x) >> 6;
    const float bl = bias[lane];
    for (int i = gw; i < N; i += nw) {
        const float scd = sc_d[i];
        float es = sc_s[i] + scd;
        es = es > 0.f ? es : 0.2f * es;   // self loop
        float m = es;
        float denom = 1.f;
        float acc = bf2f(Hb[(size_t)i * 64 + lane]);
        const int jb = rowptr[i], je = rowptr[i + 1];
        int j = jb;
        for (; j + 4 <= je; j += 4) {
            const int s0 = col[j], s1 = col[j + 1], s2 = col[j + 2], s3 = col[j + 3];
            float e0 = sc_s[s0] + scd;
            float e1 = sc_s[s1] + scd;
            float e2 = sc_s[s2] + scd;
            float e3 = sc_s[s3] + scd;
            e0 = e0 > 0.f ? e0 : 0.2f * e0;
            e1 = e1 > 0.f ? e1 : 0.2f * e1;
            e2 = e2 > 0.f ? e2 : 0.2f * e2;
            e3 = e3 > 0.f ? e3 : 0.2f * e3;
            const float h0 = bf2f(Hb[(size_t)s0 * 64 + lane]);
            const float h1 = bf2f(Hb[(size_t)s1 * 64 + lane]);
            const float h2 = bf2f(Hb[(size_t)s2 * 64 + lane]);
            const float h3 = bf2f(Hb[(size_t)s3 * 64 + lane]);
            const float mn = fmaxf(fmaxf(fmaxf(e0, e1), fmaxf(e2, e3)), m);
            const float scale = __expf(m - mn);
            const float w0 = __expf(e0 - mn);
            const float w1 = __expf(e1 - mn);
            const float w2 = __expf(e2 - mn);
            const float w3 = __expf(e3 - mn);
            denom = denom * scale + ((w0 + w1) + (w2 + w3));
            acc = acc * scale + w0 * h0 + w1 * h1 + w2 * h2 + w3 * h3;
            m = mn;
        }
        for (; j < je; j++) {
            const int s0 = col[j];
            float e0 = sc_s[s0] + scd;
            e0 = e0 > 0.f ? e0 : 0.2f * e0;
            const float h0 = bf2f(Hb[(size_t)s0 * 64 + lane]);
            const float mn = fmaxf(e0, m);
            const float scale = __expf(m - mn);
            const float w0 = __expf(e0 - mn);
            denom = denom * scale + w0;
            acc = acc * scale + w0 * h0;
            m = mn;
        }
        float o = acc / denom + bl;
        if (RELU) o = o > 0.f ? o : 0.f;
        Out[(size_t)i * 64 + lane] = o;
    }
}

// ---------------- pooling (batch is sorted: run-length accumulate) ----------------

__global__ void pool_kernel(const float* __restrict__ H, const int* __restrict__ batch,
                            float* __restrict__ sums, int* __restrict__ cnts, int N) {
    const int CHUNK = 256;
    const int lane = threadIdx.x & 63;
    int gw = (blockIdx.x * blockDim.x + threadIdx.x) >> 6;
    const int nw = (gridDim.x * blockDim.x) >> 6;
    const int nchunks = (N + CHUNK - 1) / CHUNK;
    for (int c = gw; c < nchunks; c += nw) {
        const int lo = c * CHUNK;
        const int hi = min(lo + CHUNK, N);
        int curb = batch[lo];
        float acc = 0.f;
        int cnt = 0;
        for (int n = lo; n < hi; n++) {
            int b = batch[n];
            if (b != curb) {
                unsafeAtomicAdd(&sums[(size_t)curb * 64 + lane], acc);
                if (lane == 0) atomicAdd(&cnts[curb], cnt);
                acc = 0.f; cnt = 0; curb = b;
            }
            acc += H[(size_t)n * 64 + lane];
            cnt++;
        }
        unsafeAtomicAdd(&sums[(size_t)curb * 64 + lane], acc);
        if (lane == 0) atomicAdd(&cnts[curb], cnt);
    }
}

// ---------------- final MLP + log_softmax ----------------
__global__ void mlp_kernel(const float* __restrict__ sums, const int* __restrict__ cnts,
                           const float* __restrict__ lw, const float* __restrict__ lb,
                           const float* __restrict__ cw, const float* __restrict__ cb,
                           float* __restrict__ out) {
    __shared__ float gv[64];
    __shared__ float z[32];
    __shared__ float logits[6];
    const int g = blockIdx.x;
    const int t = threadIdx.x;

    float cnt = (float)cnts[g];
    cnt = cnt > 1.f ? cnt : 1.f;
    gv[t] = sums[(size_t)g * 64 + t] / cnt;
    __syncthreads();

    if (t < 32) {
        float acc = lb[t];
#pragma unroll
        for (int k = 0; k < 64; k++) acc += gv[k] * lw[k * 32 + t];
        z[t] = acc > 0.f ? acc : 0.f;
    }
    __syncthreads();
    if (t < 6) {
        float acc = cb[t];
#pragma unroll
        for (int k = 0; k < 32; k++) acc += z[k] * cw[k * 6 + t];
        logits[t] = acc;
    }
    __syncthreads();
    if (t == 0) {
        float m = logits[0];
#pragma unroll
        for (int i = 1; i < 6; i++) m = fmaxf(m, logits[i]);
        float s = 0.f;
#pragma unroll
        for (int i = 0; i < 6; i++) s += expf(logits[i] - m);
        float lse = m + logf(s);
#pragma unroll
        for (int i = 0; i < 6; i++) out[(size_t)g * 6 + i] = logits[i] - lse;
    }
}

// ---------------- launch ----------------

extern "C" void kernel_launch(void* const* d_in, const int* in_sizes, int n_in,
                              void* d_out, int out_size, void* d_ws, size_t ws_size,
                              hipStream_t stream) {
    const float* x    = (const float*)d_in[0];
    const int*   ei   = (const int*)d_in[1];
    const int*   batch= (const int*)d_in[2];
    const float* W1   = (const float*)d_in[3];
    const float* as1  = (const float*)d_in[4];
    const float* ad1  = (const float*)d_in[5];
    const float* b1   = (const float*)d_in[6];
    const float* W2   = (const float*)d_in[7];
    const float* as2  = (const float*)d_in[8];
    const float* ad2  = (const float*)d_in[9];
    const float* b2   = (const float*)d_in[10];
    const float* lw   = (const float*)d_in[11];
    const float* lb   = (const float*)d_in[12];
    const float* cw   = (const float*)d_in[13];
    const float* cb   = (const float*)d_in[14];
    float* out = (float*)d_out;

    const int N  = in_sizes[0] / 128;
    const int E  = in_sizes[1] / 2;
    const int G  = out_size / 6;

    char* ws = (char*)d_ws;
    size_t off = 0;
    auto alloc = [&](size_t bytes) {
        void* p = ws + off;
        off += (bytes + 255) & ~size_t(255);
        return p;
    };
    float*          hB     = (float*)alloc((size_t)N * 64 * 4);
    unsigned short* Hb     = (unsigned short*)alloc((size_t)N * 64 * 2);
    float*          sc_s   = (float*)alloc((size_t)N * 4);
    float*          sc_d   = (float*)alloc((size_t)N * 4);
    int*            cnt    = (int*)alloc((size_t)N * 4);
    int*            cursor = (int*)alloc((size_t)N * 4);
    int*            rowptr = (int*)alloc((size_t)(N + 1) * 4);
    int*            colidx = (int*)alloc((size_t)E * 4);
    float*          psum   = (float*)alloc((size_t)G * 64 * 4);
    int*            pcnt   = (int*)alloc((size_t)G * 4);
    (void)ws_size;

    const int TB = 256;
    const int gemm_grid = (N + 63) / 64;

    // ---- CSR build by dst ----
    hipMemsetAsync(cnt, 0, (size_t)N * 4, stream);
    hipMemsetAsync(cursor, 0, (size_t)N * 4, stream);
    hist_kernel<<<2048, TB, 0, stream>>>(ei + E, cnt, E);
    scan_kernel<<<1, 1024, 0, stream>>>(cnt, rowptr, N);
    scatter_kernel<<<2048, TB, 0, stream>>>(ei, rowptr, cursor, colidx, E, N, 8);

    // ---- layer 1 ----
    gat_gemm_kernel<128><<<gemm_grid, TB, 0, stream>>>(x, W1, as1, ad1, Hb, sc_s, sc_d, N);
    gat_fused_agg<true><<<2048, TB, 0, stream>>>(rowptr, colidx, sc_s, sc_d, Hb, b1, hB, N);

    // ---- layer 2 ----
    gat_gemm_kernel<64><<<gemm_grid, TB, 0, stream>>>(hB, W2, as2, ad2, Hb, sc_s, sc_d, N);
    gat_fused_agg<false><<<2048, TB, 0, stream>>>(rowptr, colidx, sc_s, sc_d, Hb, b2, hB, N);

    // ---- pooling + MLP head ----
    hipMemsetAsync(psum, 0, (size_t)G * 64 * 4, stream);
    hipMemsetAsync(pcnt, 0, (size_t)G * 4, stream);
    pool_kernel<<<128, TB, 0, stream>>>(hB, batch, psum, pcnt, N);
    mlp_kernel<<<G, 64, 0, stream>>>(psum, pcnt, lw, lb, cw, cb, out);
}

// Round 6
// 744.748 us; speedup vs baseline: 4.4347x; 1.2269x over previous
//
#include <hip/hip_runtime.h>

// ---------------- bf16 helpers ----------------

__device__ __forceinline__ unsigned short f2bf(float f) {
    unsigned u = __float_as_uint(f);
    unsigned r = (u + 0x7FFFu + ((u >> 16) & 1u)) >> 16;
    return (unsigned short)r;
}
__device__ __forceinline__ float bf2f(unsigned short u) {
    return __uint_as_float(((unsigned)u) << 16);
}

// ---------------- node GEMM + attention scores ----------------
// One 64-row tile per block. X tile staged in LDS via coalesced per-lane
// float4 loads (NO wave-uniform global loads -> no unroll-hoist spill).
// Each wave computes 16 rows as 4 groups of 4 independent FMA chains.
template<int K>
__global__ __launch_bounds__(256, 2)
void gat_gemm_kernel(const float* __restrict__ X, const float* __restrict__ W,
                     const float* __restrict__ a_s, const float* __restrict__ a_d,
                     unsigned short* __restrict__ Hb, float* __restrict__ sc_s,
                     float* __restrict__ sc_d, int nrows) {
    __shared__ float Wl[K * 64];
    __shared__ float Xl[64 * K];

    const int tid = threadIdx.x;
    const int tile0 = blockIdx.x * 64;

    for (int i = tid; i < K * 64 / 4; i += 256)
        reinterpret_cast<float4*>(Wl)[i] = reinterpret_cast<const float4*>(W)[i];
    for (int i = tid; i < 64 * K / 4; i += 256) {
        const int row = i / (K / 4);
        const int gr = tile0 + row;
        float4 v = make_float4(0.f, 0.f, 0.f, 0.f);
        if (gr < nrows) v = reinterpret_cast<const float4*>(X)[(size_t)gr * (K / 4) + (i % (K / 4))];
        reinterpret_cast<float4*>(Xl)[i] = v;
    }
    __syncthreads();

    const int lane = tid & 63;
    const int wave = tid >> 6;
    const float asl = a_s[lane];
    const float adl = a_d[lane];

#pragma unroll
    for (int g = 0; g < 4; g++) {
        const int r0 = wave * 16 + g * 4;
        if (tile0 + r0 >= nrows) break;
        float acc0 = 0.f, acc1 = 0.f, acc2 = 0.f, acc3 = 0.f;
        const float* xp0 = Xl + (size_t)(r0 + 0) * K;
        const float* xp1 = Xl + (size_t)(r0 + 1) * K;
        const float* xp2 = Xl + (size_t)(r0 + 2) * K;
        const float* xp3 = Xl + (size_t)(r0 + 3) * K;
#pragma unroll 2
        for (int k = 0; k < K; k += 4) {
            const float4 a = *reinterpret_cast<const float4*>(xp0 + k);
            const float4 b = *reinterpret_cast<const float4*>(xp1 + k);
            const float4 c = *reinterpret_cast<const float4*>(xp2 + k);
            const float4 d = *reinterpret_cast<const float4*>(xp3 + k);
            const float w0 = Wl[(k + 0) * 64 + lane];
            const float w1 = Wl[(k + 1) * 64 + lane];
            const float w2 = Wl[(k + 2) * 64 + lane];
            const float w3 = Wl[(k + 3) * 64 + lane];
            acc0 += a.x * w0 + a.y * w1 + a.z * w2 + a.w * w3;
            acc1 += b.x * w0 + b.y * w1 + b.z * w2 + b.w * w3;
            acc2 += c.x * w0 + c.y * w1 + c.z * w2 + c.w * w3;
            acc3 += d.x * w0 + d.y * w1 + d.z * w2 + d.w * w3;
        }
        const float accs[4] = {acc0, acc1, acc2, acc3};
#pragma unroll
        for (int r = 0; r < 4; r++) {
            const int gr = tile0 + r0 + r;
            if (gr >= nrows) break;
            Hb[(size_t)gr * 64 + lane] = f2bf(accs[r]);
            float ps = accs[r] * asl;
            float pd = accs[r] * adl;
#pragma unroll
            for (int off = 32; off; off >>= 1) {
                ps += __shfl_down(ps, off);
                pd += __shfl_down(pd, off);
            }
            if (lane == 0) {
                sc_s[gr] = ps;
                sc_d[gr] = pd;
            }
        }
    }
}

// ---------------- CSR build ----------------

__global__ void hist_kernel(const int* __restrict__ dst, int* __restrict__ cnt, int E) {
    const int tid = blockIdx.x * blockDim.x + threadIdx.x;
    const int stride = gridDim.x * blockDim.x;
    const int E4 = E >> 2;
    for (int i = tid; i < E4; i += stride) {
        int4 d = reinterpret_cast<const int4*>(dst)[i];
        atomicAdd(&cnt[d.x], 1);
        atomicAdd(&cnt[d.y], 1);
        atomicAdd(&cnt[d.z], 1);
        atomicAdd(&cnt[d.w], 1);
    }
    for (int i = (E4 << 2) + tid; i < E; i += stride) atomicAdd(&cnt[dst[i]], 1);
}

// ---- parallel 3-stage exclusive scan over cnt[0..N) -> rowptr[0..N] ----
#define SCAN_TILE 1024

__global__ void scan_partial_kernel(const int* __restrict__ cnt, int* __restrict__ partial, int N) {
    __shared__ int red[256];
    const int b = blockIdx.x;
    const int lo = b * SCAN_TILE;
    const int hi = min(lo + SCAN_TILE, N);
    int s = 0;
    for (int i = lo + threadIdx.x; i < hi; i += 256) s += cnt[i];
    red[threadIdx.x] = s;
    __syncthreads();
    for (int off = 128; off; off >>= 1) {
        if (threadIdx.x < off) red[threadIdx.x] += red[threadIdx.x + off];
        __syncthreads();
    }
    if (threadIdx.x == 0) partial[b] = red[0];
}

// exclusive scan of partial[0..nb) in one block (nb <= 1024)
__global__ void scan_spine_kernel(int* __restrict__ partial, int nb) {
    __shared__ int s[1024];
    const int t = threadIdx.x;
    const int v = (t < nb) ? partial[t] : 0;
    s[t] = v;
    __syncthreads();
    for (int off = 1; off < 1024; off <<= 1) {
        int u = (t >= off) ? s[t - off] : 0;
        __syncthreads();
        s[t] += u;
        __syncthreads();
    }
    if (t < nb) partial[t] = s[t] - v;
}

__global__ void scan_emit_kernel(const int* __restrict__ cnt, const int* __restrict__ partial,
                                 int* __restrict__ rowptr, int N, int E) {
    __shared__ int red[256];
    const int b = blockIdx.x;
    const int t = threadIdx.x;
    const int base = b * SCAN_TILE + t * 4;   // SCAN_TILE/256 = 4 per thread
    int v[4];
    int s = 0;
#pragma unroll
    for (int k = 0; k < 4; k++) {
        const int i = base + k;
        v[k] = (i < N) ? cnt[i] : 0;
        s += v[k];
    }
    red[t] = s;
    __syncthreads();
    for (int off = 1; off < 256; off <<= 1) {
        int u = (t >= off) ? red[t - off] : 0;
        __syncthreads();
        red[t] += u;
        __syncthreads();
    }
    int excl = red[t] - s + partial[b];
#pragma unroll
    for (int k = 0; k < 4; k++) {
        const int i = base + k;
        if (i < N) rowptr[i] = excl;
        excl += v[k];
    }
    if (b == 0 && t == 0) rowptr[N] = E;   // total in-degree == E
}

// dst-windowed scatter: pass p only places edges with dst in window p, so col[]
// writes land in a cache-resident window (kills write-allocate blowup).
__global__ void scatter_kernel(const int* __restrict__ ei, const int* __restrict__ rowptr,
                               int* __restrict__ cursor, int* __restrict__ col,
                               int E, int N, int npass) {
    const int tid = blockIdx.x * blockDim.x + threadIdx.x;
    const int stride = gridDim.x * blockDim.x;
    const int win = (N + npass - 1) / npass;
    for (int p = 0; p < npass; p++) {
        const int lo = p * win;
        const int hi = min(lo + win, N);
        for (int e = tid; e < E; e += stride) {
            int d = ei[E + e];
            if (d >= lo && d < hi) {
                int pos = rowptr[d] + atomicAdd(&cursor[d], 1);
                col[pos] = ei[e];
            }
        }
    }
}

// ---------------- fused per-node online-softmax aggregation ----------------
template<bool RELU>
__global__ void gat_fused_agg(const int* __restrict__ rowptr, const int* __restrict__ col,
                              const float* __restrict__ sc_s, const float* __restrict__ sc_d,
                              const unsigned short* __restrict__ Hb, const float* __restrict__ bias,
                              float* __restrict__ Out, int N) {
    const int lane = threadIdx.x & 63;
    int gw = (blockIdx.x * blockDim.x + threadIdx.x) >> 6;
    const int nw = (gridDim.x * blockDim.x) >> 6;
    const float bl = bias[lane];
    for (int i = gw; i < N; i += nw) {
        const float scd = sc_d[i];
        float es = sc_s[i] + scd;
        es = es > 0.f ? es : 0.2f * es;   // self loop
        float m = es;
        float denom = 1.f;
        float acc = bf2f(Hb[(size_t)i * 64 + lane]);
        const int jb = rowptr[i], je = rowptr[i + 1];
        int j = jb;
        // 8-wide main loop: 8 independent gather chains in flight
        for (; j + 8 <= je; j += 8) {
            int s[8];
#pragma unroll
            for (int q = 0; q < 8; q++) s[q] = col[j + q];
            float e[8], h[8];
#pragma unroll
            for (int q = 0; q < 8; q++) {
                float ev = sc_s[s[q]] + scd;
                e[q] = ev > 0.f ? ev : 0.2f * ev;
                h[q] = bf2f(Hb[(size_t)s[q] * 64 + lane]);
            }
            float mn = m;
#pragma unroll
            for (int q = 0; q < 8; q++) mn = fmaxf(mn, e[q]);
            const float scale = __expf(m - mn);
            float w[8];
#pragma unroll
            for (int q = 0; q < 8; q++) w[q] = __expf(e[q] - mn);
            float dsum = 0.f, hsum = 0.f;
#pragma unroll
            for (int q = 0; q < 8; q++) {
                dsum += w[q];
                hsum += w[q] * h[q];
            }
            denom = denom * scale + dsum;
            acc = acc * scale + hsum;
            m = mn;
        }
        for (; j + 4 <= je; j += 4) {
            int s[4];
#pragma unroll
            for (int q = 0; q < 4; q++) s[q] = col[j + q];
            float e[4], h[4];
#pragma unroll
            for (int q = 0; q < 4; q++) {
                float ev = sc_s[s[q]] + scd;
                e[q] = ev > 0.f ? ev : 0.2f * ev;
                h[q] = bf2f(Hb[(size_t)s[q] * 64 + lane]);
            }
            float mn = fmaxf(fmaxf(fmaxf(e[0], e[1]), fmaxf(e[2], e[3])), m);
            const float scale = __expf(m - mn);
            float dsum = 0.f, hsum = 0.f;
#pragma unroll
            for (int q = 0; q < 4; q++) {
                float wq = __expf(e[q] - mn);
                dsum += wq;
                hsum += wq * h[q];
            }
            denom = denom * scale + dsum;
            acc = acc * scale + hsum;
            m = mn;
        }
        for (; j < je; j++) {
            const int s0 = col[j];
            float e0 = sc_s[s0] + scd;
            e0 = e0 > 0.f ? e0 : 0.2f * e0;
            const float h0 = bf2f(Hb[(size_t)s0 * 64 + lane]);
            const float mn = fmaxf(e0, m);
            const float scale = __expf(m - mn);
            const float w0 = __expf(e0 - mn);
            denom = denom * scale + w0;
            acc = acc * scale + w0 * h0;
            m = mn;
        }
        float o = acc / denom + bl;
        if (RELU) o = o > 0.f ? o : 0.f;
        Out[(size_t)i * 64 + lane] = o;
    }
}

// ---------------- pooling (batch is sorted: run-length accumulate) ----------------

__global__ void pool_kernel(const float* __restrict__ H, const int* __restrict__ batch,
                            float* __restrict__ sums, int* __restrict__ cnts, int N) {
    const int CHUNK = 256;
    const int lane = threadIdx.x & 63;
    int gw = (blockIdx.x * blockDim.x + threadIdx.x) >> 6;
    const int nw = (gridDim.x * blockDim.x) >> 6;
    const int nchunks = (N + CHUNK - 1) / CHUNK;
    for (int c = gw; c < nchunks; c += nw) {
        const int lo = c * CHUNK;
        const int hi = min(lo + CHUNK, N);
        int curb = batch[lo];
        float acc = 0.f;
        int cnt = 0;
        for (int n = lo; n < hi; n++) {
            int b = batch[n];
            if (b != curb) {
                unsafeAtomicAdd(&sums[(size_t)curb * 64 + lane], acc);
                if (lane == 0) atomicAdd(&cnts[curb], cnt);
                acc = 0.f; cnt = 0; curb = b;
            }
            acc += H[(size_t)n * 64 + lane];
            cnt++;
        }
        unsafeAtomicAdd(&sums[(size_t)curb * 64 + lane], acc);
        if (lane == 0) atomicAdd(&cnts[curb], cnt);
    }
}

// ---------------- final MLP + log_softmax ----------------
__global__ void mlp_kernel(const float* __restrict__ sums, const int* __restrict__ cnts,
                           const float* __restrict__ lw, const float* __restrict__ lb,
                           const float* __restrict__ cw, const float* __restrict__ cb,
                           float* __restrict__ out) {
    __shared__ float gv[64];
    __shared__ float z[32];
    __shared__ float logits[6];
    const int g = blockIdx.x;
    const int t = threadIdx.x;

    float cnt = (float)cnts[g];
    cnt = cnt > 1.f ? cnt : 1.f;
    gv[t] = sums[(size_t)g * 64 + t] / cnt;
    __syncthreads();

    if (t < 32) {
        float acc = lb[t];
#pragma unroll
        for (int k = 0; k < 64; k++) acc += gv[k] * lw[k * 32 + t];
        z[t] = acc > 0.f ? acc : 0.f;
    }
    __syncthreads();
    if (t < 6) {
        float acc = cb[t];
#pragma unroll
        for (int k = 0; k < 32; k++) acc += z[k] * cw[k * 6 + t];
        logits[t] = acc;
    }
    __syncthreads();
    if (t == 0) {
        float m = logits[0];
#pragma unroll
        for (int i = 1; i < 6; i++) m = fmaxf(m, logits[i]);
        float s = 0.f;
#pragma unroll
        for (int i = 0; i < 6; i++) s += expf(logits[i] - m);
        float lse = m + logf(s);
#pragma unroll
        for (int i = 0; i < 6; i++) out[(size_t)g * 6 + i] = logits[i] - lse;
    }
}

// ---------------- launch ----------------

extern "C" void kernel_launch(void* const* d_in, const int* in_sizes, int n_in,
                              void* d_out, int out_size, void* d_ws, size_t ws_size,
                              hipStream_t stream) {
    const float* x    = (const float*)d_in[0];
    const int*   ei   = (const int*)d_in[1];
    const int*   batch= (const int*)d_in[2];
    const float* W1   = (const float*)d_in[3];
    const float* as1  = (const float*)d_in[4];
    const float* ad1  = (const float*)d_in[5];
    const float* b1   = (const float*)d_in[6];
    const float* W2   = (const float*)d_in[7];
    const float* as2  = (const float*)d_in[8];
    const float* ad2  = (const float*)d_in[9];
    const float* b2   = (const float*)d_in[10];
    const float* lw   = (const float*)d_in[11];
    const float* lb   = (const float*)d_in[12];
    const float* cw   = (const float*)d_in[13];
    const float* cb   = (const float*)d_in[14];
    float* out = (float*)d_out;

    const int N  = in_sizes[0] / 128;
    const int E  = in_sizes[1] / 2;
    const int G  = out_size / 6;

    char* ws = (char*)d_ws;
    size_t off = 0;
    auto alloc = [&](size_t bytes) {
        void* p = ws + off;
        off += (bytes + 255) & ~size_t(255);
        return p;
    };
    float*          hB     = (float*)alloc((size_t)N * 64 * 4);
    unsigned short* Hb     = (unsigned short*)alloc((size_t)N * 64 * 2);
    float*          sc_s   = (float*)alloc((size_t)N * 4);
    float*          sc_d   = (float*)alloc((size_t)N * 4);
    int*            cnt    = (int*)alloc((size_t)N * 4);
    int*            cursor = (int*)alloc((size_t)N * 4);
    int*            rowptr = (int*)alloc((size_t)(N + 1) * 4);
    int*            colidx = (int*)alloc((size_t)E * 4);
    int*            partial= (int*)alloc((size_t)1024 * 4);
    float*          psum   = (float*)alloc((size_t)G * 64 * 4);
    int*            pcnt   = (int*)alloc((size_t)G * 4);
    (void)ws_size;

    const int TB = 256;
    const int gemm_grid = (N + 63) / 64;
    const int scan_blocks = (N + SCAN_TILE - 1) / SCAN_TILE;

    // ---- CSR build by dst ----
    hipMemsetAsync(cnt, 0, (size_t)N * 4, stream);
    hipMemsetAsync(cursor, 0, (size_t)N * 4, stream);
    hist_kernel<<<2048, TB, 0, stream>>>(ei + E, cnt, E);
    scan_partial_kernel<<<scan_blocks, 256, 0, stream>>>(cnt, partial, N);
    scan_spine_kernel<<<1, 1024, 0, stream>>>(partial, scan_blocks);
    scan_emit_kernel<<<scan_blocks, 256, 0, stream>>>(cnt, partial, rowptr, N, E);
    scatter_kernel<<<2048, TB, 0, stream>>>(ei, rowptr, cursor, colidx, E, N, 8);

    // ---- layer 1 ----
    gat_gemm_kernel<128><<<gemm_grid, TB, 0, stream>>>(x, W1, as1, ad1, Hb, sc_s, sc_d, N);
    gat_fused_agg<true><<<2048, TB, 0, stream>>>(rowptr, colidx, sc_s, sc_d, Hb, b1, hB, N);

    // ---- layer 2 ----
    gat_gemm_kernel<64><<<gemm_grid, TB, 0, stream>>>(hB, W2, as2, ad2, Hb, sc_s, sc_d, N);
    gat_fused_agg<false><<<2048, TB, 0, stream>>>(rowptr, colidx, sc_s, sc_d, Hb, b2, hB, N);

    // ---- pooling + MLP head ----
    hipMemsetAsync(psum, 0, (size_t)G * 64 * 4, stream);
    hipMemsetAsync(pcnt, 0, (size_t)G * 4, stream);
    pool_kernel<<<128, TB, 0, stream>>>(hB, batch, psum, pcnt, N);
    mlp_kernel<<<G, 64, 0, stream>>>(psum, pcnt, lw, lb, cw, cb, out);
}

// Round 7
// 718.439 us; speedup vs baseline: 4.5971x; 1.0366x over previous
//
#include <hip/hip_runtime.h>

// ---------------- bf16 helpers ----------------

__device__ __forceinline__ unsigned short f2bf(float f) {
    unsigned u = __float_as_uint(f);
    unsigned r = (u + 0x7FFFu + ((u >> 16) & 1u)) >> 16;
    return (unsigned short)r;
}
__device__ __forceinline__ float bf2f(unsigned short u) {
    return __uint_as_float(((unsigned)u) << 16);
}

// ---------------- node GEMM + attention scores ----------------
// One 64-row tile per block. X tile staged in LDS via coalesced per-lane
// float4 loads (NO wave-uniform global loads -> no unroll-hoist spill).
// Each wave computes 16 rows as 4 groups of 4 independent FMA chains.
template<int K>
__global__ __launch_bounds__(256, 2)
void gat_gemm_kernel(const float* __restrict__ X, const float* __restrict__ W,
                     const float* __restrict__ a_s, const float* __restrict__ a_d,
                     unsigned short* __restrict__ Hb, float* __restrict__ sc_s,
                     float* __restrict__ sc_d, int nrows) {
    __shared__ float Wl[K * 64];
    __shared__ float Xl[64 * K];

    const int tid = threadIdx.x;
    const int tile0 = blockIdx.x * 64;

    for (int i = tid; i < K * 64 / 4; i += 256)
        reinterpret_cast<float4*>(Wl)[i] = reinterpret_cast<const float4*>(W)[i];
    for (int i = tid; i < 64 * K / 4; i += 256) {
        const int row = i / (K / 4);
        const int gr = tile0 + row;
        float4 v = make_float4(0.f, 0.f, 0.f, 0.f);
        if (gr < nrows) v = reinterpret_cast<const float4*>(X)[(size_t)gr * (K / 4) + (i % (K / 4))];
        reinterpret_cast<float4*>(Xl)[i] = v;
    }
    __syncthreads();

    const int lane = tid & 63;
    const int wave = tid >> 6;
    const float asl = a_s[lane];
    const float adl = a_d[lane];

#pragma unroll
    for (int g = 0; g < 4; g++) {
        const int r0 = wave * 16 + g * 4;
        if (tile0 + r0 >= nrows) break;
        float acc0 = 0.f, acc1 = 0.f, acc2 = 0.f, acc3 = 0.f;
        const float* xp0 = Xl + (size_t)(r0 + 0) * K;
        const float* xp1 = Xl + (size_t)(r0 + 1) * K;
        const float* xp2 = Xl + (size_t)(r0 + 2) * K;
        const float* xp3 = Xl + (size_t)(r0 + 3) * K;
#pragma unroll 2
        for (int k = 0; k < K; k += 4) {
            const float4 a = *reinterpret_cast<const float4*>(xp0 + k);
            const float4 b = *reinterpret_cast<const float4*>(xp1 + k);
            const float4 c = *reinterpret_cast<const float4*>(xp2 + k);
            const float4 d = *reinterpret_cast<const float4*>(xp3 + k);
            const float w0 = Wl[(k + 0) * 64 + lane];
            const float w1 = Wl[(k + 1) * 64 + lane];
            const float w2 = Wl[(k + 2) * 64 + lane];
            const float w3 = Wl[(k + 3) * 64 + lane];
            acc0 += a.x * w0 + a.y * w1 + a.z * w2 + a.w * w3;
            acc1 += b.x * w0 + b.y * w1 + b.z * w2 + b.w * w3;
            acc2 += c.x * w0 + c.y * w1 + c.z * w2 + c.w * w3;
            acc3 += d.x * w0 + d.y * w1 + d.z * w2 + d.w * w3;
        }
        const float accs[4] = {acc0, acc1, acc2, acc3};
#pragma unroll
        for (int r = 0; r < 4; r++) {
            const int gr = tile0 + r0 + r;
            if (gr >= nrows) break;
            Hb[(size_t)gr * 64 + lane] = f2bf(accs[r]);
            float ps = accs[r] * asl;
            float pd = accs[r] * adl;
#pragma unroll
            for (int off = 32; off; off >>= 1) {
                ps += __shfl_down(ps, off);
                pd += __shfl_down(pd, off);
            }
            if (lane == 0) {
                sc_s[gr] = ps;
                sc_d[gr] = pd;
            }
        }
    }
}

// ---------------- CSR build ----------------

__global__ void hist_kernel(const int* __restrict__ dst, int* __restrict__ cnt, int E) {
    const int tid = blockIdx.x * blockDim.x + threadIdx.x;
    const int stride = gridDim.x * blockDim.x;
    const int E4 = E >> 2;
    for (int i = tid; i < E4; i += stride) {
        int4 d = reinterpret_cast<const int4*>(dst)[i];
        atomicAdd(&cnt[d.x], 1);
        atomicAdd(&cnt[d.y], 1);
        atomicAdd(&cnt[d.z], 1);
        atomicAdd(&cnt[d.w], 1);
    }
    for (int i = (E4 << 2) + tid; i < E; i += stride) atomicAdd(&cnt[dst[i]], 1);
}

// ---- parallel 3-stage exclusive scan over cnt[0..N) -> rowptr[0..N] ----
#define SCAN_TILE 1024

__global__ void scan_partial_kernel(const int* __restrict__ cnt, int* __restrict__ partial, int N) {
    __shared__ int red[256];
    const int b = blockIdx.x;
    const int lo = b * SCAN_TILE;
    const int hi = min(lo + SCAN_TILE, N);
    int s = 0;
    for (int i = lo + threadIdx.x; i < hi; i += 256) s += cnt[i];
    red[threadIdx.x] = s;
    __syncthreads();
    for (int off = 128; off; off >>= 1) {
        if (threadIdx.x < off) red[threadIdx.x] += red[threadIdx.x + off];
        __syncthreads();
    }
    if (threadIdx.x == 0) partial[b] = red[0];
}

// exclusive scan of partial[0..nb) in one block (nb <= 1024)
__global__ void scan_spine_kernel(int* __restrict__ partial, int nb) {
    __shared__ int s[1024];
    const int t = threadIdx.x;
    const int v = (t < nb) ? partial[t] : 0;
    s[t] = v;
    __syncthreads();
    for (int off = 1; off < 1024; off <<= 1) {
        int u = (t >= off) ? s[t - off] : 0;
        __syncthreads();
        s[t] += u;
        __syncthreads();
    }
    if (t < nb) partial[t] = s[t] - v;
}

__global__ void scan_emit_kernel(const int* __restrict__ cnt, const int* __restrict__ partial,
                                 int* __restrict__ rowptr, int N, int E) {
    __shared__ int red[256];
    const int b = blockIdx.x;
    const int t = threadIdx.x;
    const int base = b * SCAN_TILE + t * 4;   // SCAN_TILE/256 = 4 per thread
    int v[4];
    int s = 0;
#pragma unroll
    for (int k = 0; k < 4; k++) {
        const int i = base + k;
        v[k] = (i < N) ? cnt[i] : 0;
        s += v[k];
    }
    red[t] = s;
    __syncthreads();
    for (int off = 1; off < 256; off <<= 1) {
        int u = (t >= off) ? red[t - off] : 0;
        __syncthreads();
        red[t] += u;
        __syncthreads();
    }
    int excl = red[t] - s + partial[b];
#pragma unroll
    for (int k = 0; k < 4; k++) {
        const int i = base + k;
        if (i < N) rowptr[i] = excl;
        excl += v[k];
    }
    if (b == 0 && t == 0) rowptr[N] = E;   // total in-degree == E
}

// XCD-private windowed scatter, single pass: group g = blockIdx&7 (round-robin
// XCD heuristic) places only edges with dst in window g. Every col/cursor line
// is written by exactly ONE XCD -> stays dirty-resident in that L2, evicted
// once. (The previous time-sequential windows had all 8 XCDs sharing lines ->
// 64B memory-side writeback per 4B store, WRITE_SIZE 197MB.)
__global__ void scatter_kernel(const int* __restrict__ ei, const int* __restrict__ rowptr,
                               int* __restrict__ cursor, int* __restrict__ col,
                               int E, int N) {
    const int g = blockIdx.x & 7;
    const int win = (N + 7) / 8;
    const int lo = g * win;
    const int hi = min(lo + win, N);
    const int gtid = (blockIdx.x >> 3) * blockDim.x + threadIdx.x;
    const int gstride = (gridDim.x >> 3) * blockDim.x;
    for (int e = gtid; e < E; e += gstride) {
        const int d = ei[E + e];
        if (d >= lo && d < hi) {
            const int pos = rowptr[d] + atomicAdd(&cursor[d], 1);
            col[pos] = ei[e];
        }
    }
}

// ---------------- fused per-node online-softmax aggregation ----------------
template<bool RELU>
__global__ void gat_fused_agg(const int* __restrict__ rowptr, const int* __restrict__ col,
                              const float* __restrict__ sc_s, const float* __restrict__ sc_d,
                              const unsigned short* __restrict__ Hb, const float* __restrict__ bias,
                              float* __restrict__ Out, int N) {
    const int lane = threadIdx.x & 63;
    int gw = (blockIdx.x * blockDim.x + threadIdx.x) >> 6;
    const int nw = (gridDim.x * blockDim.x) >> 6;
    const float bl = bias[lane];
    for (int i = gw; i < N; i += nw) {
        const float scd = sc_d[i];
        float es = sc_s[i] + scd;
        es = es > 0.f ? es : 0.2f * es;   // self loop
        float m = es;
        float denom = 1.f;
        float acc = bf2f(Hb[(size_t)i * 64 + lane]);
        const int jb = rowptr[i], je = rowptr[i + 1];
        int j = jb;
        // 8-wide main loop: 8 independent gather chains in flight
        for (; j + 8 <= je; j += 8) {
            int s[8];
#pragma unroll
            for (int q = 0; q < 8; q++) s[q] = col[j + q];
            float e[8], h[8];
#pragma unroll
            for (int q = 0; q < 8; q++) {
                float ev = sc_s[s[q]] + scd;
                e[q] = ev > 0.f ? ev : 0.2f * ev;
                h[q] = bf2f(Hb[(size_t)s[q] * 64 + lane]);
            }
            float mn = m;
#pragma unroll
            for (int q = 0; q < 8; q++) mn = fmaxf(mn, e[q]);
            const float scale = __expf(m - mn);
            float w[8];
#pragma unroll
            for (int q = 0; q < 8; q++) w[q] = __expf(e[q] - mn);
            float dsum = 0.f, hsum = 0.f;
#pragma unroll
            for (int q = 0; q < 8; q++) {
                dsum += w[q];
                hsum += w[q] * h[q];
            }
            denom = denom * scale + dsum;
            acc = acc * scale + hsum;
            m = mn;
        }
        for (; j + 4 <= je; j += 4) {
            int s[4];
#pragma unroll
            for (int q = 0; q < 4; q++) s[q] = col[j + q];
            float e[4], h[4];
#pragma unroll
            for (int q = 0; q < 4; q++) {
                float ev = sc_s[s[q]] + scd;
                e[q] = ev > 0.f ? ev : 0.2f * ev;
                h[q] = bf2f(Hb[(size_t)s[q] * 64 + lane]);
            }
            float mn = fmaxf(fmaxf(fmaxf(e[0], e[1]), fmaxf(e[2], e[3])), m);
            const float scale = __expf(m - mn);
            float dsum = 0.f, hsum = 0.f;
#pragma unroll
            for (int q = 0; q < 4; q++) {
                float wq = __expf(e[q] - mn);
                dsum += wq;
                hsum += wq * h[q];
            }
            denom = denom * scale + dsum;
            acc = acc * scale + hsum;
            m = mn;
        }
        for (; j < je; j++) {
            const int s0 = col[j];
            float e0 = sc_s[s0] + scd;
            e0 = e0 > 0.f ? e0 : 0.2f * e0;
            const float h0 = bf2f(Hb[(size_t)s0 * 64 + lane]);
            const float mn = fmaxf(e0, m);
            const float scale = __expf(m - mn);
            const float w0 = __expf(e0 - mn);
            denom = denom * scale + w0;
            acc = acc * scale + w0 * h0;
            m = mn;
        }
        float o = acc / denom + bl;
        if (RELU) o = o > 0.f ? o : 0.f;
        Out[(size_t)i * 64 + lane] = o;
    }
}

// ---------------- pooling (batch is sorted: run-length accumulate) ----------------

__global__ void pool_kernel(const float* __restrict__ H, const int* __restrict__ batch,
                            float* __restrict__ sums, int* __restrict__ cnts, int N) {
    const int CHUNK = 256;
    const int lane = threadIdx.x & 63;
    int gw = (blockIdx.x * blockDim.x + threadIdx.x) >> 6;
    const int nw = (gridDim.x * blockDim.x) >> 6;
    const int nchunks = (N + CHUNK - 1) / CHUNK;
    for (int c = gw; c < nchunks; c += nw) {
        const int lo = c * CHUNK;
        const int hi = min(lo + CHUNK, N);
        int curb = batch[lo];
        float acc = 0.f;
        int cnt = 0;
        for (int n = lo; n < hi; n++) {
            int b = batch[n];
            if (b != curb) {
                unsafeAtomicAdd(&sums[(size_t)curb * 64 + lane], acc);
                if (lane == 0) atomicAdd(&cnts[curb], cnt);
                acc = 0.f; cnt = 0; curb = b;
            }
            acc += H[(size_t)n * 64 + lane];
            cnt++;
        }
        unsafeAtomicAdd(&sums[(size_t)curb * 64 + lane], acc);
        if (lane == 0) atomicAdd(&cnts[curb], cnt);
    }
}

// ---------------- final MLP + log_softmax ----------------
__global__ void mlp_kernel(const float* __restrict__ sums, const int* __restrict__ cnts,
                           const float* __restrict__ lw, const float* __restrict__ lb,
                           const float* __restrict__ cw, const float* __restrict__ cb,
                           float* __restrict__ out) {
    __shared__ float gv[64];
    __shared__ float z[32];
    __shared__ float logits[6];
    const int g = blockIdx.x;
    const int t = threadIdx.x;

    float cnt = (float)cnts[g];
    cnt = cnt > 1.f ? cnt : 1.f;
    gv[t] = sums[(size_t)g * 64 + t] / cnt;
    __syncthreads();

    if (t < 32) {
        float acc = lb[t];
#pragma unroll
        for (int k = 0; k < 64; k++) acc += gv[k] * lw[k * 32 + t];
        z[t] = acc > 0.f ? acc : 0.f;
    }
    __syncthreads();
    if (t < 6) {
        float acc = cb[t];
#pragma unroll
        for (int k = 0; k < 32; k++) acc += z[k] * cw[k * 6 + t];
        logits[t] = acc;
    }
    __syncthreads();
    if (t == 0) {
        float m = logits[0];
#pragma unroll
        for (int i = 1; i < 6; i++) m = fmaxf(m, logits[i]);
        float s = 0.f;
#pragma unroll
        for (int i = 0; i < 6; i++) s += expf(logits[i] - m);
        float lse = m + logf(s);
#pragma unroll
        for (int i = 0; i < 6; i++) out[(size_t)g * 6 + i] = logits[i] - lse;
    }
}

// ---------------- launch ----------------

extern "C" void kernel_launch(void* const* d_in, const int* in_sizes, int n_in,
                              void* d_out, int out_size, void* d_ws, size_t ws_size,
                              hipStream_t stream) {
    const float* x    = (const float*)d_in[0];
    const int*   ei   = (const int*)d_in[1];
    const int*   batch= (const int*)d_in[2];
    const float* W1   = (const float*)d_in[3];
    const float* as1  = (const float*)d_in[4];
    const float* ad1  = (const float*)d_in[5];
    const float* b1   = (const float*)d_in[6];
    const float* W2   = (const float*)d_in[7];
    const float* as2  = (const float*)d_in[8];
    const float* ad2  = (const float*)d_in[9];
    const float* b2   = (const float*)d_in[10];
    const float* lw   = (const float*)d_in[11];
    const float* lb   = (const float*)d_in[12];
    const float* cw   = (const float*)d_in[13];
    const float* cb   = (const float*)d_in[14];
    float* out = (float*)d_out;

    const int N  = in_sizes[0] / 128;
    const int E  = in_sizes[1] / 2;
    const int G  = out_size / 6;

    char* ws = (char*)d_ws;
    size_t off = 0;
    auto alloc = [&](size_t bytes) {
        void* p = ws + off;
        off += (bytes + 255) & ~size_t(255);
        return p;
    };
    float*          hB     = (float*)alloc((size_t)N * 64 * 4);
    unsigned short* Hb     = (unsigned short*)alloc((size_t)N * 64 * 2);
    float*          sc_s   = (float*)alloc((size_t)N * 4);
    float*          sc_d   = (float*)alloc((size_t)N * 4);
    int*            cnt    = (int*)alloc((size_t)N * 4);
    int*            cursor = (int*)alloc((size_t)N * 4);
    int*            rowptr = (int*)alloc((size_t)(N + 1) * 4);
    int*            colidx = (int*)alloc((size_t)E * 4);
    int*            partial= (int*)alloc((size_t)1024 * 4);
    float*          psum   = (float*)alloc((size_t)G * 64 * 4);
    int*            pcnt   = (int*)alloc((size_t)G * 4);
    (void)ws_size;

    const int TB = 256;
    const int gemm_grid = (N + 63) / 64;
    const int scan_blocks = (N + SCAN_TILE - 1) / SCAN_TILE;

    // ---- CSR build by dst ----
    hipMemsetAsync(cnt, 0, (size_t)N * 4, stream);
    hipMemsetAsync(cursor, 0, (size_t)N * 4, stream);
    hist_kernel<<<2048, TB, 0, stream>>>(ei + E, cnt, E);
    scan_partial_kernel<<<scan_blocks, 256, 0, stream>>>(cnt, partial, N);
    scan_spine_kernel<<<1, 1024, 0, stream>>>(partial, scan_blocks);
    scan_emit_kernel<<<scan_blocks, 256, 0, stream>>>(cnt, partial, rowptr, N, E);
    scatter_kernel<<<4096, TB, 0, stream>>>(ei, rowptr, cursor, colidx, E, N);

    // ---- layer 1 ----
    gat_gemm_kernel<128><<<gemm_grid, TB, 0, stream>>>(x, W1, as1, ad1, Hb, sc_s, sc_d, N);
    gat_fused_agg<true><<<2048, TB, 0, stream>>>(rowptr, colidx, sc_s, sc_d, Hb, b1, hB, N);

    // ---- layer 2 ----
    gat_gemm_kernel<64><<<gemm_grid, TB, 0, stream>>>(hB, W2, as2, ad2, Hb, sc_s, sc_d, N);
    gat_fused_agg<false><<<2048, TB, 0, stream>>>(rowptr, colidx, sc_s, sc_d, Hb, b2, hB, N);

    // ---- pooling + MLP head ----
    hipMemsetAsync(psum, 0, (size_t)G * 64 * 4, stream);
    hipMemsetAsync(pcnt, 0, (size_t)G * 4, stream);
    pool_kernel<<<128, TB, 0, stream>>>(hB, batch, psum, pcnt, N);
    mlp_kernel<<<G, 64, 0, stream>>>(psum, pcnt, lw, lb, cw, cb, out);
}